// Round 8
// baseline (1813.192 us; speedup 1.0000x reference)
//
#include <hip/hip_runtime.h>
#include <hip/hip_bf16.h>

#define NU_ 50000
#define NI_ 50000
#define NN  (NU_ + NI_)   // 100000
#define DD  64
#define KK  4
#define EE  1000000
#define SCAN_B ((NN + 255) / 256)   // 391

#define P_RANGES 8
#define RANGE_SZ ((NN + P_RANGES - 1) / P_RANGES)  // 12500

// ---------- XCD-range-partitioned degree histogram (batched over k) ----------
// Range g -> XCD g (blockIdx.x fastest in linear dispatch): all atomics on a
// cnt line resolve inside one XCD's L2 (no cross-XCD line ping-pong).
// Per-XCD working set: 12500 ints x 4 k = 200 KB -> fits trivially.
__global__ __launch_bounds__(256) void k_hist2(const int* __restrict__ rows,
                                               const int* __restrict__ cols,
                                               int* __restrict__ cnt4) {
    const int g = blockIdx.x;                 // 0..7
    const int k = blockIdx.z;
    const int lo = g * RANGE_SZ;
    int e = blockIdx.y * 256 + threadIdx.x;
    if (e >= EE) return;
    int a = rows[(size_t)k * EE + e], b = cols[(size_t)k * EE + e];
    if ((unsigned)a >= (unsigned)NU_ || (unsigned)b >= (unsigned)NI_) return; // defensive
    b += NU_;
    int* cnt = cnt4 + (size_t)k * NN;
    if ((unsigned)(a - lo) < (unsigned)RANGE_SZ) atomicAdd(&cnt[a], 1);
    if ((unsigned)(b - lo) < (unsigned)RANGE_SZ) atomicAdd(&cnt[b], 1);
}

// ---------- pass 1: per-block sums of cnt (batched over k) ----------
__global__ __launch_bounds__(256) void k_bsum(const int* __restrict__ cnt4,
                                              int* __restrict__ bsum4) {
    __shared__ int s[256];
    const int k = blockIdx.y;
    int i = blockIdx.x * 256 + threadIdx.x;
    s[threadIdx.x] = (i < NN) ? cnt4[(size_t)k * NN + i] : 0;
    __syncthreads();
    #pragma unroll
    for (int off = 128; off > 0; off >>= 1) {
        if (threadIdx.x < off) s[threadIdx.x] += s[threadIdx.x + off];
        __syncthreads();
    }
    if (threadIdx.x == 0) bsum4[k * SCAN_B + blockIdx.x] = s[0];
}

// ---------- pass 2: scan 391 block sums per k (4 blocks) ----------
__global__ __launch_bounds__(512) void k_sscan(const int* __restrict__ bsum4,
                                               int* __restrict__ bofs4) {
    __shared__ int s[512];
    const int k = blockIdx.x;
    int tid = threadIdx.x;
    s[tid] = (tid < SCAN_B) ? bsum4[k * SCAN_B + tid] : 0;
    __syncthreads();
    #pragma unroll
    for (int off = 1; off < 512; off <<= 1) {
        int v = (tid >= off) ? s[tid - off] : 0;
        __syncthreads();
        s[tid] += v;
        __syncthreads();
    }
    if (tid < SCAN_B) bofs4[k * SCAN_B + tid] = (tid > 0) ? s[tid - 1] : 0;
}

// ---------- pass 3: intra-block scan -> row_ptr/cursor/dinv (batched) ----------
__global__ __launch_bounds__(256) void k_apply(const int* __restrict__ cnt4,
                                               const int* __restrict__ bofs4,
                                               int* __restrict__ row_ptr4,
                                               int* __restrict__ cursor4,
                                               float* __restrict__ dinv4) {
    __shared__ int s[256];
    const int k = blockIdx.y;
    int i = blockIdx.x * 256 + threadIdx.x;
    int v = (i < NN) ? cnt4[(size_t)k * NN + i] : 0;
    s[threadIdx.x] = v;
    __syncthreads();
    #pragma unroll
    for (int off = 1; off < 256; off <<= 1) {
        int t = (threadIdx.x >= off) ? s[threadIdx.x - off] : 0;
        __syncthreads();
        s[threadIdx.x] += t;
        __syncthreads();
    }
    if (i < NN) {
        int incl = s[threadIdx.x] + bofs4[k * SCAN_B + blockIdx.x];
        int excl = incl - v;
        row_ptr4[(size_t)k * (NN + 1) + i] = excl;
        cursor4[(size_t)k * NN + i] = excl;
        dinv4[(size_t)k * NN + i] = rsqrtf((float)v + 1e-7f);
        if (i == NN - 1) row_ptr4[(size_t)k * (NN + 1) + NN] = incl;
    }
}

// ---------- XCD-range-partitioned scatter into CSR adjacency ----------
// R6 post-mortem: z=4 batching put 4 k x (1MB adj + 50KB cursor) = 4.2MB in
// each XCD's 4MB L2 -> line-merge broke (WRITE_SIZE 345MB). Launch with z=2
// (k-offset kbase): 2.1MB/XCD fits -> each adj line accumulates all 16
// entries in-L2, one 64B writeback per line.
__global__ __launch_bounds__(256) void k_scatter2(const int* __restrict__ rows,
                                                  const int* __restrict__ cols,
                                                  int* __restrict__ cursor4,
                                                  int* __restrict__ adj4,
                                                  int kbase) {
    const int g = blockIdx.x;                 // 0..7
    const int k = kbase + blockIdx.z;
    const int lo = g * RANGE_SZ;
    int e = blockIdx.y * 256 + threadIdx.x;
    if (e >= EE) return;
    int a = rows[(size_t)k * EE + e], b = cols[(size_t)k * EE + e];
    if ((unsigned)a >= (unsigned)NU_ || (unsigned)b >= (unsigned)NI_) return; // defensive
    b += NU_;
    int* cursor = cursor4 + (size_t)k * NN;
    int* adj = adj4 + (size_t)k * 2 * EE;
    if ((unsigned)(a - lo) < (unsigned)RANGE_SZ) {
        int p = atomicAdd(&cursor[a], 1);
        adj[p] = b;
    }
    if ((unsigned)(b - lo) < (unsigned)RANGE_SZ) {
        int q = atomicAdd(&cursor[b], 1);
        adj[q] = a;
    }
}

// ---------- operand pre-scale for k=0 only: hbuf = dinv0*(relu(x)+bias) ----------
// (k>=1 hbuf is produced fused inside k_row of the previous iteration.)
__global__ __launch_bounds__(256) void k_prep(const float* __restrict__ x,
                                              const float* __restrict__ bias,
                                              const float* __restrict__ dinv,
                                              float* __restrict__ hbuf) {
    int i = blockIdx.x * 256 + threadIdx.x;   // float4 index, NN*DD/4 total
    int node = i >> 4;                        // 16 float4 per row
    float dv = dinv[node];
    const float4 xv = ((const float4*)x)[i];
    const float4 bv = ((const float4*)bias)[i & 15];
    float4 o;
    o.x = dv * (fmaxf(xv.x, 0.f) + bv.x);
    o.y = dv * (fmaxf(xv.y, 0.f) + bv.y);
    o.z = dv * (fmaxf(xv.z, 0.f) + bv.z);
    o.w = dv * (fmaxf(xv.w, 0.f) + bv.w);
    ((float4*)hbuf)[i] = o;
}

// ---------- gather-accumulate core (quarter-wave per row) ----------
// Full-16 chunks take a fully-unrolled 16-gather path with 4 independent
// accumulator chains (16 loads in flight; ~84% of edges at Poisson(20));
// remainder chunks use the dynamic unroll-4 path. Trips stay optimal (R3
// lesson: padding to 16 cost more than deep flight gained).
#define GATHER_ROW(SRC, accOut)                                                \
    float4 aA = {0,0,0,0}, aB = {0,0,0,0}, aC = {0,0,0,0}, aD = {0,0,0,0};     \
    for (int base = start; base < end; base += 16) {                           \
        int n = end - base; if (n > 16) n = 16;                                \
        int idx = (l16 < n) ? adj[base + l16] : 0;                             \
        if (n == 16) {                                                         \
            _Pragma("unroll")                                                  \
            for (int j = 0; j < 16; j += 4) {                                  \
                int n0 = __shfl(idx, lb | j);                                  \
                int n1 = __shfl(idx, lb | (j + 1));                            \
                int n2 = __shfl(idx, lb | (j + 2));                            \
                int n3 = __shfl(idx, lb | (j + 3));                            \
                const float4 v0 = *(const float4*)&SRC[(size_t)n0 * DD + l16 * 4]; \
                const float4 v1 = *(const float4*)&SRC[(size_t)n1 * DD + l16 * 4]; \
                const float4 v2 = *(const float4*)&SRC[(size_t)n2 * DD + l16 * 4]; \
                const float4 v3 = *(const float4*)&SRC[(size_t)n3 * DD + l16 * 4]; \
                aA.x += v0.x; aA.y += v0.y; aA.z += v0.z; aA.w += v0.w;        \
                aB.x += v1.x; aB.y += v1.y; aB.z += v1.z; aB.w += v1.w;        \
                aC.x += v2.x; aC.y += v2.y; aC.z += v2.z; aC.w += v2.w;        \
                aD.x += v3.x; aD.y += v3.y; aD.z += v3.z; aD.w += v3.w;        \
            }                                                                  \
        } else {                                                               \
            int j = 0;                                                         \
            for (; j + 3 < n; j += 4) {                                        \
                int n0 = __shfl(idx, lb | j);                                  \
                int n1 = __shfl(idx, lb | (j + 1));                            \
                int n2 = __shfl(idx, lb | (j + 2));                            \
                int n3 = __shfl(idx, lb | (j + 3));                            \
                const float4 v0 = *(const float4*)&SRC[(size_t)n0 * DD + l16 * 4]; \
                const float4 v1 = *(const float4*)&SRC[(size_t)n1 * DD + l16 * 4]; \
                const float4 v2 = *(const float4*)&SRC[(size_t)n2 * DD + l16 * 4]; \
                const float4 v3 = *(const float4*)&SRC[(size_t)n3 * DD + l16 * 4]; \
                aA.x += v0.x; aA.y += v0.y; aA.z += v0.z; aA.w += v0.w;        \
                aB.x += v1.x; aB.y += v1.y; aB.z += v1.z; aB.w += v1.w;        \
                aC.x += v2.x; aC.y += v2.y; aC.z += v2.z; aC.w += v2.w;        \
                aD.x += v3.x; aD.y += v3.y; aD.z += v3.z; aD.w += v3.w;        \
            }                                                                  \
            for (; j < n; j++) {                                               \
                int nb = __shfl(idx, lb | j);                                  \
                const float4 v = *(const float4*)&SRC[(size_t)nb * DD + l16 * 4]; \
                aA.x += v.x; aA.y += v.y; aA.z += v.z; aA.w += v.w;            \
            }                                                                  \
        }                                                                      \
    }                                                                          \
    float4 accOut = {(aA.x + aB.x) + (aC.x + aD.x),                            \
                     (aA.y + aB.y) + (aC.y + aD.y),                            \
                     (aA.z + aB.z) + (aC.z + aD.z),                            \
                     (aA.w + aB.w) + (aC.w + aD.w)};

// ---------- hop 1: edge = L h ----------
// Writes out_e = dr*acc (edges[k] output) and h2buf = dr^2*acc (pre-scaled
// hop-2 operand -> hop 2 needs no per-neighbor dinv gather or weight shfl).
__global__ __launch_bounds__(256) void k_pullA(const int* __restrict__ row_ptr,
                                               const int* __restrict__ adj,
                                               const float* __restrict__ dinv,
                                               const float* __restrict__ hbuf,
                                               float* __restrict__ out_e,
                                               float* __restrict__ h2buf) {
    const int wave = threadIdx.x >> 6;
    const int lane = threadIdx.x & 63;
    const int sub  = lane >> 4;
    const int l16  = lane & 15;
    const int lb   = sub << 4;
    const int row  = (blockIdx.x * 4 + wave) * 4 + sub;   // NN%16==0
    const int start = row_ptr[row];
    const int end   = row_ptr[row + 1];
    GATHER_ROW(hbuf, acc)
    const float dr = dinv[row];
    float4 e = {dr * acc.x, dr * acc.y, dr * acc.z, dr * acc.w};
    *(float4*)&out_e[(size_t)row * DD + l16 * 4] = e;
    float4 e2 = {dr * e.x, dr * e.y, dr * e.z, dr * e.w};
    *(float4*)&h2buf[(size_t)row * DD + l16 * 4] = e2;
}

// ---------- hop 2: node = L edge ----------
__global__ __launch_bounds__(256) void k_pullB(const int* __restrict__ row_ptr,
                                               const int* __restrict__ adj,
                                               const float* __restrict__ dinv,
                                               const float* __restrict__ h2buf,
                                               float* __restrict__ out_n) {
    const int wave = threadIdx.x >> 6;
    const int lane = threadIdx.x & 63;
    const int sub  = lane >> 4;
    const int l16  = lane & 15;
    const int lb   = sub << 4;
    const int row  = (blockIdx.x * 4 + wave) * 4 + sub;
    const int start = row_ptr[row];
    const int end   = row_ptr[row + 1];
    GATHER_ROW(h2buf, acc)
    const float dr = dinv[row];
    float4 o = {dr * acc.x, dr * acc.y, dr * acc.z, dr * acc.w};
    *(float4*)&out_n[(size_t)row * DD + l16 * 4] = o;
}

// ---------- fused: softmax(node) -> fc1 -> fusion gate -> x_new ----------
// Also FUSES next iteration's operand pre-scale: writes
// hbuf_next = dinv_next * (relu(x_new) + hgc1_bias) while x_new is in regs.
#define BC(v, d) __uint_as_float(__builtin_amdgcn_readlane(__float_as_uint(v), (d)))

__global__ __launch_bounds__(256) void k_row(
    const float* __restrict__ node, const float* __restrict__ xsrc,
    const float* __restrict__ fc1W, const float* __restrict__ fusW,
    const float* __restrict__ l1b, const float* __restrict__ l2w,
    const float* __restrict__ l2b, const float* __restrict__ hgb,
    const float* __restrict__ dinv_next, float* __restrict__ out_nodes,
    float* __restrict__ hbuf_next) {
    const int wave = threadIdx.x >> 6;
    const int lane = threadIdx.x & 63;

    float wf[DD], wu[DD];
    #pragma unroll
    for (int d = 0; d < DD; d += 4) {
        *(float4*)&wf[d] = *(const float4*)&fc1W[(size_t)lane * DD + d];
        *(float4*)&wu[d] = *(const float4*)&fusW[(size_t)lane * DD + d];
    }
    const float b1v = l1b[lane];
    const float l2v = l2w[lane];
    const float b2v = l2b[0];
    const float hgv = hgb[lane];

    for (int row = blockIdx.x * 4 + wave; row < NN; row += gridDim.x * 4) {
        const size_t base = (size_t)row * DD + lane;
        float v = node[base];
        // --- softmax over D=64 ---
        float m = v;
        #pragma unroll
        for (int s = 1; s < 64; s <<= 1) m = fmaxf(m, __shfl_xor(m, s));
        float ev = __expf(v - m);
        float sum = ev;
        #pragma unroll
        for (int s = 1; s < 64; s <<= 1) sum += __shfl_xor(sum, s);
        float sm = ev / sum;
        // --- fc1 ---
        float n0 = 0, n1 = 0, n2 = 0, n3 = 0;
        #pragma unroll
        for (int d = 0; d < DD; d += 4) {
            n0 = fmaf(BC(sm, d),     wf[d],     n0);
            n1 = fmaf(BC(sm, d + 1), wf[d + 1], n1);
            n2 = fmaf(BC(sm, d + 2), wf[d + 2], n2);
            n3 = fmaf(BC(sm, d + 3), wf[d + 3], n3);
        }
        float nf = (n0 + n1) + (n2 + n3);
        float xc = xsrc[base];
        // --- fusion branch: xc ---
        float a0 = 0, a1 = 0, a2 = 0, a3 = 0;
        #pragma unroll
        for (int d = 0; d < DD; d += 4) {
            a0 = fmaf(BC(xc, d),     wu[d],     a0);
            a1 = fmaf(BC(xc, d + 1), wu[d + 1], a1);
            a2 = fmaf(BC(xc, d + 2), wu[d + 2], a2);
            a3 = fmaf(BC(xc, d + 3), wu[d + 3], a3);
        }
        float tt = tanhf(((a0 + a1) + (a2 + a3)) + b1v);
        float p = tt * l2v;
        #pragma unroll
        for (int s = 1; s < 64; s <<= 1) p += __shfl_xor(p, s);
        float s_x = p + b2v;
        // --- fusion branch: nf ---
        a0 = 0; a1 = 0; a2 = 0; a3 = 0;
        #pragma unroll
        for (int d = 0; d < DD; d += 4) {
            a0 = fmaf(BC(nf, d),     wu[d],     a0);
            a1 = fmaf(BC(nf, d + 1), wu[d + 1], a1);
            a2 = fmaf(BC(nf, d + 2), wu[d + 2], a2);
            a3 = fmaf(BC(nf, d + 3), wu[d + 3], a3);
        }
        tt = tanhf(((a0 + a1) + (a2 + a3)) + b1v);
        p = tt * l2v;
        #pragma unroll
        for (int s = 1; s < 64; s <<= 1) p += __shfl_xor(p, s);
        float s_n = p + b2v;
        // --- gate + blend ---
        float mm = fmaxf(s_x, s_n);
        float e0 = __expf(s_x - mm), e1 = __expf(s_n - mm);
        float inv = 1.0f / (e0 + e1);
        float xn = (e0 * xc + e1 * nf) * inv;
        out_nodes[base] = xn;
        // --- fused next-iteration operand pre-scale ---
        if (hbuf_next) {
            float dv = dinv_next[row];
            hbuf_next[base] = dv * (fmaxf(xn, 0.f) + hgv);
        }
    }
}

extern "C" void kernel_launch(void* const* d_in, const int* in_sizes, int n_in,
                              void* d_out, int out_size, void* d_ws, size_t ws_size,
                              hipStream_t stream) {
    const float* x    = (const float*)d_in[0];
    const float* b1   = (const float*)d_in[1];  // hgc1_bias
    const float* fc1W = (const float*)d_in[2];
    const float* fusW = (const float*)d_in[3];  // fus_l1_W
    const float* l1b  = (const float*)d_in[4];
    const float* l2w  = (const float*)d_in[5];
    const float* l2b  = (const float*)d_in[6];
    const int* rows = (const int*)d_in[7];
    const int* cols = (const int*)d_in[8];
    float* out = (float*)d_out;

    const int ND = NN * DD;  // 6,400,000

    // workspace layout (~90 MB)
    float* hbuf     = (float*)d_ws;                       // NN*DD
    float* h2buf    = hbuf + (size_t)NN * DD;             // NN*DD
    float* dinv4    = h2buf + (size_t)NN * DD;            // 4*NN
    int*   cnt4     = (int*)(dinv4 + (size_t)4 * NN);     // 4*NN
    int*   row_ptr4 = cnt4 + (size_t)4 * NN;              // 4*(NN+1)
    int*   cursor4  = row_ptr4 + (size_t)4 * (NN + 1);    // 4*NN
    int*   bsum4    = cursor4 + (size_t)4 * NN;           // 4*SCAN_B
    int*   bofs4    = bsum4 + 4 * SCAN_B;                 // 4*SCAN_B
    int*   adj4     = bofs4 + 4 * SCAN_B;                 // 4*2*EE

    // --- batched CSR build for ALL 4 sub-graphs (input-only, no carry dep) ---
    hipMemsetAsync(cnt4, 0, (size_t)4 * NN * sizeof(int), stream);
    {
        dim3 g(P_RANGES, (EE + 255) / 256, KK);
        k_hist2<<<g, 256, 0, stream>>>(rows, cols, cnt4);
    }
    {
        dim3 g(SCAN_B, KK);
        k_bsum<<<g, 256, 0, stream>>>(cnt4, bsum4);
    }
    k_sscan<<<KK, 512, 0, stream>>>(bsum4, bofs4);
    {
        dim3 g(SCAN_B, KK);
        k_apply<<<g, 256, 0, stream>>>(cnt4, bofs4, row_ptr4, cursor4, dinv4);
    }
    // scatter in two z=2 launches: per-XCD L2 working set 2.1MB < 4MB ->
    // line-merge preserved (R6: z=4 was 4.2MB and broke it, WRITE 345MB)
    {
        dim3 g(P_RANGES, (EE + 255) / 256, 2);
        k_scatter2<<<g, 256, 0, stream>>>(rows, cols, cursor4, adj4, 0);
        k_scatter2<<<g, 256, 0, stream>>>(rows, cols, cursor4, adj4, 2);
    }

    // hbuf for k=0 from the input x
    k_prep<<<ND / 4 / 256, 256, 0, stream>>>(x, b1, dinv4, hbuf);

    for (int k = 0; k < KK; k++) {
        const int*   rp = row_ptr4 + (size_t)k * (NN + 1);
        const int*   aj = adj4 + (size_t)k * 2 * EE;
        const float* dv = dinv4 + (size_t)k * NN;
        const float* xk = (k == 0) ? x : out + (size_t)(k - 1) * ND;  // carry
        float* out_n = out + (size_t)k * ND;         // nodes[k] slot
        float* out_e = out + (size_t)(KK + k) * ND;  // edges[k] slot

        // edge = L h  (writes edges[k] and pre-scaled hop-2 operand)
        k_pullA<<<NN / 16, 256, 0, stream>>>(rp, aj, dv, hbuf, out_e, h2buf);

        // node = L edge
        k_pullB<<<NN / 16, 256, 0, stream>>>(rp, aj, dv, h2buf, out_n);

        // softmax -> fc1 -> fusion gate -> x_new (in place); fused prep of
        // next iteration's hbuf
        const float* dvn = (k < KK - 1) ? dinv4 + (size_t)(k + 1) * NN : nullptr;
        float* hbn = (k < KK - 1) ? hbuf : nullptr;
        k_row<<<1024, 256, 0, stream>>>(out_n, xk, fc1W, fusW, l1b, l2w, l2b,
                                        b1, dvn, out_n, hbn);
    }
}

// Round 9
// 1507.695 us; speedup vs baseline: 1.2026x; 1.2026x over previous
//
#include <hip/hip_runtime.h>
#include <hip/hip_bf16.h>

#define NU_ 50000
#define NI_ 50000
#define NN  (NU_ + NI_)   // 100000
#define DD  64
#define KK  4
#define EE  1000000

#define P_RANGES 8
#define RANGE_SZ ((NN + P_RANGES - 1) / P_RANGES)  // 12500

#define SLOT 64   // slots per node; Poisson(20) -> P(deg>=64) ~ 3e-15

// ---------- fused count+place scatter into slot adjacency ----------
// R8 post-mortem: device-scope int atomics write through to the coherent
// point (~31B fabric write each; hist2 WRITE 249MB despite perfect
// partitioning) -> partitioning can't make them cheap, so pay them ONCE.
// s = atomicAdd(&cnt[node]) is simultaneously the placement cursor and the
// degree counter: kills k_hist2 (327us) + the whole prefix-scan chain.
// XCD-range-partitioned (range g -> XCD g via bid%8 round-robin): per-XCD
// write set = 12500 nodes x 256B slots + 50KB cnt = 3.25MB < 4MB L2 ->
// adj line-merge preserved (R0 mechanism). Per-k launch (R6 lesson: k>=2
// batching overflows the 4MB L2 and breaks merging).
__global__ __launch_bounds__(256) void k_sscatter(const int* __restrict__ rows,
                                                  const int* __restrict__ cols,
                                                  int* __restrict__ cnt4,
                                                  int* __restrict__ adj4,
                                                  int k) {
    const int g = blockIdx.x;                 // 0..7
    const int lo = g * RANGE_SZ;
    int e = blockIdx.y * 256 + threadIdx.x;
    if (e >= EE) return;
    int a = rows[(size_t)k * EE + e], b = cols[(size_t)k * EE + e];
    if ((unsigned)a >= (unsigned)NU_ || (unsigned)b >= (unsigned)NI_) return; // defensive
    b += NU_;
    int* cnt = cnt4 + (size_t)k * NN;
    int* adj = adj4 + (size_t)k * NN * SLOT;
    if ((unsigned)(a - lo) < (unsigned)RANGE_SZ) {
        int s = atomicAdd(&cnt[a], 1);
        if (s < SLOT) adj[(size_t)a * SLOT + s] = b;   // cap: never hit for Poisson(20)
    }
    if ((unsigned)(b - lo) < (unsigned)RANGE_SZ) {
        int s = atomicAdd(&cnt[b], 1);
        if (s < SLOT) adj[(size_t)b * SLOT + s] = a;
    }
}

// ---------- dinv4 = rsqrt(cnt4 + 1e-7) for all k (elementwise) ----------
__global__ __launch_bounds__(256) void k_dinv(const int* __restrict__ cnt4,
                                              float* __restrict__ dinv4) {
    int i = blockIdx.x * 256 + threadIdx.x;
    if (i < KK * NN) dinv4[i] = rsqrtf((float)cnt4[i] + 1e-7f);
}

// ---------- operand pre-scale for k=0 only: hbuf = dinv0*(relu(x)+bias) ----------
// (k>=1 hbuf is produced fused inside k_row of the previous iteration.)
__global__ __launch_bounds__(256) void k_prep(const float* __restrict__ x,
                                              const float* __restrict__ bias,
                                              const float* __restrict__ dinv,
                                              float* __restrict__ hbuf) {
    int i = blockIdx.x * 256 + threadIdx.x;   // float4 index, NN*DD/4 total
    int node = i >> 4;                        // 16 float4 per row
    float dv = dinv[node];
    const float4 xv = ((const float4*)x)[i];
    const float4 bv = ((const float4*)bias)[i & 15];
    float4 o;
    o.x = dv * (fmaxf(xv.x, 0.f) + bv.x);
    o.y = dv * (fmaxf(xv.y, 0.f) + bv.y);
    o.z = dv * (fmaxf(xv.z, 0.f) + bv.z);
    o.w = dv * (fmaxf(xv.w, 0.f) + bv.w);
    ((float4*)hbuf)[i] = o;
}

// ---------- gather-accumulate core (quarter-wave per row) ----------
// Slot layout: every 16-int chunk is one exactly-aligned 64B line.
// Full-16 chunks take a fully-unrolled 16-gather path with 4 independent
// accumulator chains; remainder uses dynamic unroll-4 (R3 lesson: no pad).
#define GATHER_ROW(SRC, accOut)                                                \
    float4 aA = {0,0,0,0}, aB = {0,0,0,0}, aC = {0,0,0,0}, aD = {0,0,0,0};     \
    for (int base = start; base < end; base += 16) {                           \
        int n = end - base; if (n > 16) n = 16;                                \
        int idx = (l16 < n) ? adj[base + l16] : 0;                             \
        if (n == 16) {                                                         \
            _Pragma("unroll")                                                  \
            for (int j = 0; j < 16; j += 4) {                                  \
                int n0 = __shfl(idx, lb | j);                                  \
                int n1 = __shfl(idx, lb | (j + 1));                            \
                int n2 = __shfl(idx, lb | (j + 2));                            \
                int n3 = __shfl(idx, lb | (j + 3));                            \
                const float4 v0 = *(const float4*)&SRC[(size_t)n0 * DD + l16 * 4]; \
                const float4 v1 = *(const float4*)&SRC[(size_t)n1 * DD + l16 * 4]; \
                const float4 v2 = *(const float4*)&SRC[(size_t)n2 * DD + l16 * 4]; \
                const float4 v3 = *(const float4*)&SRC[(size_t)n3 * DD + l16 * 4]; \
                aA.x += v0.x; aA.y += v0.y; aA.z += v0.z; aA.w += v0.w;        \
                aB.x += v1.x; aB.y += v1.y; aB.z += v1.z; aB.w += v1.w;        \
                aC.x += v2.x; aC.y += v2.y; aC.z += v2.z; aC.w += v2.w;        \
                aD.x += v3.x; aD.y += v3.y; aD.z += v3.z; aD.w += v3.w;        \
            }                                                                  \
        } else {                                                               \
            int j = 0;                                                         \
            for (; j + 3 < n; j += 4) {                                        \
                int n0 = __shfl(idx, lb | j);                                  \
                int n1 = __shfl(idx, lb | (j + 1));                            \
                int n2 = __shfl(idx, lb | (j + 2));                            \
                int n3 = __shfl(idx, lb | (j + 3));                            \
                const float4 v0 = *(const float4*)&SRC[(size_t)n0 * DD + l16 * 4]; \
                const float4 v1 = *(const float4*)&SRC[(size_t)n1 * DD + l16 * 4]; \
                const float4 v2 = *(const float4*)&SRC[(size_t)n2 * DD + l16 * 4]; \
                const float4 v3 = *(const float4*)&SRC[(size_t)n3 * DD + l16 * 4]; \
                aA.x += v0.x; aA.y += v0.y; aA.z += v0.z; aA.w += v0.w;        \
                aB.x += v1.x; aB.y += v1.y; aB.z += v1.z; aB.w += v1.w;        \
                aC.x += v2.x; aC.y += v2.y; aC.z += v2.z; aC.w += v2.w;        \
                aD.x += v3.x; aD.y += v3.y; aD.z += v3.z; aD.w += v3.w;        \
            }                                                                  \
            for (; j < n; j++) {                                               \
                int nb = __shfl(idx, lb | j);                                  \
                const float4 v = *(const float4*)&SRC[(size_t)nb * DD + l16 * 4]; \
                aA.x += v.x; aA.y += v.y; aA.z += v.z; aA.w += v.w;            \
            }                                                                  \
        }                                                                      \
    }                                                                          \
    float4 accOut = {(aA.x + aB.x) + (aC.x + aD.x),                            \
                     (aA.y + aB.y) + (aC.y + aD.y),                            \
                     (aA.z + aB.z) + (aC.z + aD.z),                            \
                     (aA.w + aB.w) + (aC.w + aD.w)};

// ---------- hop 1: edge = L h ----------
// Writes out_e = dr*acc (edges[k] output) and h2buf = dr^2*acc (pre-scaled
// hop-2 operand -> hop 2 needs no per-neighbor dinv gather or weight shfl).
__global__ __launch_bounds__(256) void k_pullA(const int* __restrict__ cnt,
                                               const int* __restrict__ adj,
                                               const float* __restrict__ dinv,
                                               const float* __restrict__ hbuf,
                                               float* __restrict__ out_e,
                                               float* __restrict__ h2buf) {
    const int wave = threadIdx.x >> 6;
    const int lane = threadIdx.x & 63;
    const int sub  = lane >> 4;
    const int l16  = lane & 15;
    const int lb   = sub << 4;
    const int row  = (blockIdx.x * 4 + wave) * 4 + sub;   // NN%16==0
    int deg = cnt[row]; if (deg > SLOT) deg = SLOT;
    const int start = row * SLOT;
    const int end   = start + deg;
    GATHER_ROW(hbuf, acc)
    const float dr = dinv[row];
    float4 e = {dr * acc.x, dr * acc.y, dr * acc.z, dr * acc.w};
    *(float4*)&out_e[(size_t)row * DD + l16 * 4] = e;
    float4 e2 = {dr * e.x, dr * e.y, dr * e.z, dr * e.w};
    *(float4*)&h2buf[(size_t)row * DD + l16 * 4] = e2;
}

// ---------- hop 2: node = L edge ----------
__global__ __launch_bounds__(256) void k_pullB(const int* __restrict__ cnt,
                                               const int* __restrict__ adj,
                                               const float* __restrict__ dinv,
                                               const float* __restrict__ h2buf,
                                               float* __restrict__ out_n) {
    const int wave = threadIdx.x >> 6;
    const int lane = threadIdx.x & 63;
    const int sub  = lane >> 4;
    const int l16  = lane & 15;
    const int lb   = sub << 4;
    const int row  = (blockIdx.x * 4 + wave) * 4 + sub;
    int deg = cnt[row]; if (deg > SLOT) deg = SLOT;
    const int start = row * SLOT;
    const int end   = start + deg;
    GATHER_ROW(h2buf, acc)
    const float dr = dinv[row];
    float4 o = {dr * acc.x, dr * acc.y, dr * acc.z, dr * acc.w};
    *(float4*)&out_n[(size_t)row * DD + l16 * 4] = o;
}

// ---------- fused: softmax(node) -> fc1 -> fusion gate -> x_new ----------
// Also FUSES next iteration's operand pre-scale: writes
// hbuf_next = dinv_next * (relu(x_new) + hgc1_bias) while x_new is in regs.
#define BC(v, d) __uint_as_float(__builtin_amdgcn_readlane(__float_as_uint(v), (d)))

__global__ __launch_bounds__(256) void k_row(
    const float* __restrict__ node, const float* __restrict__ xsrc,
    const float* __restrict__ fc1W, const float* __restrict__ fusW,
    const float* __restrict__ l1b, const float* __restrict__ l2w,
    const float* __restrict__ l2b, const float* __restrict__ hgb,
    const float* __restrict__ dinv_next, float* __restrict__ out_nodes,
    float* __restrict__ hbuf_next) {
    const int wave = threadIdx.x >> 6;
    const int lane = threadIdx.x & 63;

    float wf[DD], wu[DD];
    #pragma unroll
    for (int d = 0; d < DD; d += 4) {
        *(float4*)&wf[d] = *(const float4*)&fc1W[(size_t)lane * DD + d];
        *(float4*)&wu[d] = *(const float4*)&fusW[(size_t)lane * DD + d];
    }
    const float b1v = l1b[lane];
    const float l2v = l2w[lane];
    const float b2v = l2b[0];
    const float hgv = hgb[lane];

    for (int row = blockIdx.x * 4 + wave; row < NN; row += gridDim.x * 4) {
        const size_t base = (size_t)row * DD + lane;
        float v = node[base];
        // --- softmax over D=64 ---
        float m = v;
        #pragma unroll
        for (int s = 1; s < 64; s <<= 1) m = fmaxf(m, __shfl_xor(m, s));
        float ev = __expf(v - m);
        float sum = ev;
        #pragma unroll
        for (int s = 1; s < 64; s <<= 1) sum += __shfl_xor(sum, s);
        float sm = ev / sum;
        // --- fc1 ---
        float n0 = 0, n1 = 0, n2 = 0, n3 = 0;
        #pragma unroll
        for (int d = 0; d < DD; d += 4) {
            n0 = fmaf(BC(sm, d),     wf[d],     n0);
            n1 = fmaf(BC(sm, d + 1), wf[d + 1], n1);
            n2 = fmaf(BC(sm, d + 2), wf[d + 2], n2);
            n3 = fmaf(BC(sm, d + 3), wf[d + 3], n3);
        }
        float nf = (n0 + n1) + (n2 + n3);
        float xc = xsrc[base];
        // --- fusion branch: xc ---
        float a0 = 0, a1 = 0, a2 = 0, a3 = 0;
        #pragma unroll
        for (int d = 0; d < DD; d += 4) {
            a0 = fmaf(BC(xc, d),     wu[d],     a0);
            a1 = fmaf(BC(xc, d + 1), wu[d + 1], a1);
            a2 = fmaf(BC(xc, d + 2), wu[d + 2], a2);
            a3 = fmaf(BC(xc, d + 3), wu[d + 3], a3);
        }
        float tt = tanhf(((a0 + a1) + (a2 + a3)) + b1v);
        float p = tt * l2v;
        #pragma unroll
        for (int s = 1; s < 64; s <<= 1) p += __shfl_xor(p, s);
        float s_x = p + b2v;
        // --- fusion branch: nf ---
        a0 = 0; a1 = 0; a2 = 0; a3 = 0;
        #pragma unroll
        for (int d = 0; d < DD; d += 4) {
            a0 = fmaf(BC(nf, d),     wu[d],     a0);
            a1 = fmaf(BC(nf, d + 1), wu[d + 1], a1);
            a2 = fmaf(BC(nf, d + 2), wu[d + 2], a2);
            a3 = fmaf(BC(nf, d + 3), wu[d + 3], a3);
        }
        tt = tanhf(((a0 + a1) + (a2 + a3)) + b1v);
        p = tt * l2v;
        #pragma unroll
        for (int s = 1; s < 64; s <<= 1) p += __shfl_xor(p, s);
        float s_n = p + b2v;
        // --- gate + blend ---
        float mm = fmaxf(s_x, s_n);
        float e0 = __expf(s_x - mm), e1 = __expf(s_n - mm);
        float inv = 1.0f / (e0 + e1);
        float xn = (e0 * xc + e1 * nf) * inv;
        out_nodes[base] = xn;
        // --- fused next-iteration operand pre-scale ---
        if (hbuf_next) {
            float dv = dinv_next[row];
            hbuf_next[base] = dv * (fmaxf(xn, 0.f) + hgv);
        }
    }
}

extern "C" void kernel_launch(void* const* d_in, const int* in_sizes, int n_in,
                              void* d_out, int out_size, void* d_ws, size_t ws_size,
                              hipStream_t stream) {
    const float* x    = (const float*)d_in[0];
    const float* b1   = (const float*)d_in[1];  // hgc1_bias
    const float* fc1W = (const float*)d_in[2];
    const float* fusW = (const float*)d_in[3];  // fus_l1_W
    const float* l1b  = (const float*)d_in[4];
    const float* l2w  = (const float*)d_in[5];
    const float* l2b  = (const float*)d_in[6];
    const int* rows = (const int*)d_in[7];
    const int* cols = (const int*)d_in[8];
    float* out = (float*)d_out;

    const int ND = NN * DD;  // 6,400,000

    // workspace layout (~157 MB)
    float* hbuf  = (float*)d_ws;                          // NN*DD
    float* h2buf = hbuf + (size_t)NN * DD;                // NN*DD
    float* dinv4 = h2buf + (size_t)NN * DD;               // 4*NN
    int*   cnt4  = (int*)(dinv4 + (size_t)KK * NN);       // 4*NN
    int*   adj4  = cnt4 + (size_t)KK * NN;                // 4*NN*SLOT (102.4 MB)

    // --- slot-CSR build: ONE atomic pass per edge-side (count == cursor) ---
    hipMemsetAsync(cnt4, 0, (size_t)KK * NN * sizeof(int), stream);
    {
        dim3 g(P_RANGES, (EE + 255) / 256);
        for (int k = 0; k < KK; k++)
            k_sscatter<<<g, 256, 0, stream>>>(rows, cols, cnt4, adj4, k);
    }
    k_dinv<<<(KK * NN + 255) / 256, 256, 0, stream>>>(cnt4, dinv4);

    // hbuf for k=0 from the input x
    k_prep<<<ND / 4 / 256, 256, 0, stream>>>(x, b1, dinv4, hbuf);

    for (int k = 0; k < KK; k++) {
        const int*   ck = cnt4 + (size_t)k * NN;
        const int*   aj = adj4 + (size_t)k * NN * SLOT;
        const float* dv = dinv4 + (size_t)k * NN;
        const float* xk = (k == 0) ? x : out + (size_t)(k - 1) * ND;  // carry
        float* out_n = out + (size_t)k * ND;         // nodes[k] slot
        float* out_e = out + (size_t)(KK + k) * ND;  // edges[k] slot

        // edge = L h  (writes edges[k] and pre-scaled hop-2 operand)
        k_pullA<<<NN / 16, 256, 0, stream>>>(ck, aj, dv, hbuf, out_e, h2buf);

        // node = L edge
        k_pullB<<<NN / 16, 256, 0, stream>>>(ck, aj, dv, h2buf, out_n);

        // softmax -> fc1 -> fusion gate -> x_new (in place); fused prep of
        // next iteration's hbuf
        const float* dvn = (k < KK - 1) ? dinv4 + (size_t)(k + 1) * NN : nullptr;
        float* hbn = (k < KK - 1) ? hbuf : nullptr;
        k_row<<<1024, 256, 0, stream>>>(out_n, xk, fc1W, fusW, l1b, l2w, l2b,
                                        b1, dvn, out_n, hbn);
    }
}